// Round 18
// baseline (190.074 us; speedup 1.0000x reference)
//
#include <hip/hip_runtime.h>

// Problem constants (from reference)
#define B_ 32
#define C_ 32
#define T_ 8192
#define N_ 256
#define P_ 6
#define TV_ (T_ - P_ + 1)   // valid conv length = 8187
#define MAGIC 0x1B171D05u   // done-word sentinel (poison 0xAA.. != MAGIC)

// ---------------------------------------------------------------------------
// decode4: chars word covering t..t+3 of row b (sum_c c * onehot).
// ---------------------------------------------------------------------------
__device__ __forceinline__ unsigned decode4(const float* __restrict__ inp,
                                            int b, int t) {
    const float* base = inp + (size_t)b * C_ * T_ + t;
    float ax = 0.f, ay = 0.f, az = 0.f, aw = 0.f;
    #pragma unroll
    for (int c = 0; c < C_; ++c) {
        float4 v = *(const float4*)(base + (size_t)c * T_);
        float fc = (float)c;
        ax += fc * v.x; ay += fc * v.y; az += fc * v.z; aw += fc * v.w;
    }
    return ((unsigned)(ax + 0.5f))
         | ((unsigned)(ay + 0.5f) << 8)
         | ((unsigned)(az + 0.5f) << 16)
         | ((unsigned)(aw + 0.5f) << 24);
}

// ---------------------------------------------------------------------------
// k_all: ONE node. Grid (ng=8, tc=8, b=32) = 2048 blocks = full residency
// (proven store geometry). ng==0 blocks produce the (b,tc) chars chunk and
// release-publish it; ng>0 blocks derive tabs (overlapping), acquire-spin on
// the done word, then run the verbatim r5 match+store loop. The store stream
// starts per-chunk as soon as that chunk is decoded — no graph edge, no
// whole-buffer wait. Bounded spin -> in-block self-decode fallback makes the
// kernel correct under ANY dispatch order (G16), since decode is idempotent.
// ---------------------------------------------------------------------------
__global__ void k_all(const float* __restrict__ inp,
                      const float* __restrict__ pat,
                      unsigned* __restrict__ chars32,
                      unsigned* __restrict__ done,
                      float* __restrict__ out) {
    __shared__ unsigned s32[258];         // chars chunk + 2 halo words
    __shared__ unsigned s_tabs[32 * 12];  // this block's 32-n tab slice
    __shared__ int s_fb;                  // fallback flag

    int ng  = blockIdx.x;                 // 0..7 (n-group; ng==0 = producer)
    int tc  = blockIdx.y;                 // 0..7 (t-chunk)
    int b   = blockIdx.z;                 // 0..31
    int tid = threadIdx.x;
    int t0  = tc << 10;
    int tb  = t0 + (tid << 2);
    int n0  = ng << 5;
    int chunk = (b << 3) | tc;
    size_t cbase = ((size_t)b * T_ + t0) >> 2;

    if (ng == 0) {
        // ---------------- producer ----------------
        unsigned w = decode4(inp, b, tb);
        s32[tid] = w;
        chars32[cbase + tid] = w;
        if (tid < 2) {                    // own halo (local only)
            int th = t0 + 1024 + (tid << 2);
            s32[256 + tid] = (th < T_) ? decode4(inp, b, th) : 0u;
        }
        __syncthreads();                  // drains all stores (vmcnt) pre-barrier
        if (tid == 0)
            __hip_atomic_store(&done[chunk], MAGIC, __ATOMIC_RELEASE,
                               __HIP_MEMORY_SCOPE_AGENT);
        // tabs for own (ng=0) slice, after publish
        if (tid < 192) {
            int nl = tid & 31, p = tid >> 5, n = n0 + nl;
            float maxv = -3.402823466e+38f, sum = 0.0f;
            unsigned mask = 0u;
            #pragma unroll
            for (int c = 0; c < C_; ++c) {
                float v = pat[((size_t)c * P_ + p) * N_ + n];
                sum += v;
                if (v > maxv) { maxv = v; mask = (1u << c); }
                else if (v == maxv) { mask |= (1u << c); }
            }
            if (!(sum > 0.0f)) mask = 0u;
            int pc = __popc(mask);
            unsigned req = (unsigned)(__ffs((int)mask) - 1);
            s_tabs[nl * 12 + p]     = (pc == 1) ? req * 0x01010101u : 0x7F7F7F7Fu;
            s_tabs[nl * 12 + 6 + p] = (pc == 0) ? 0u : 0x80808080u;
        }
        __syncthreads();
    } else {
        // ---------------- consumer ----------------
        if (tid == 0) s_fb = 0;
        if (tid < 192) {                  // tabs first: overlaps producer work
            int nl = tid & 31, p = tid >> 5, n = n0 + nl;
            float maxv = -3.402823466e+38f, sum = 0.0f;
            unsigned mask = 0u;
            #pragma unroll
            for (int c = 0; c < C_; ++c) {
                float v = pat[((size_t)c * P_ + p) * N_ + n];
                sum += v;
                if (v > maxv) { maxv = v; mask = (1u << c); }
                else if (v == maxv) { mask |= (1u << c); }
            }
            if (!(sum > 0.0f)) mask = 0u;
            int pc = __popc(mask);
            unsigned req = (unsigned)(__ffs((int)mask) - 1);
            s_tabs[nl * 12 + p]     = (pc == 1) ? req * 0x01010101u : 0x7F7F7F7Fu;
            s_tabs[nl * 12 + 6 + p] = (pc == 0) ? 0u : 0x80808080u;
        }
        __syncthreads();
        if (tid == 0) {                   // spin for own chunk
            int it = 0;
            while (__hip_atomic_load(&done[chunk], __ATOMIC_ACQUIRE,
                                     __HIP_MEMORY_SCOPE_AGENT) != MAGIC) {
                __builtin_amdgcn_s_sleep(8);
                if (++it > (1 << 16)) { s_fb = 1; break; }
            }
        }
        if (tid == 1 && tc < 7) {         // spin for halo chunk
            int it = 0;
            while (__hip_atomic_load(&done[chunk + 1], __ATOMIC_ACQUIRE,
                                     __HIP_MEMORY_SCOPE_AGENT) != MAGIC) {
                __builtin_amdgcn_s_sleep(8);
                if (++it > (1 << 16)) { s_fb = 1; break; }
            }
        }
        __syncthreads();
        if (s_fb) {                       // deadlock-proof fallback: self-decode
            s32[tid] = decode4(inp, b, tb);
            if (tid < 2) {
                int th = t0 + 1024 + (tid << 2);
                s32[256 + tid] = (th < T_) ? decode4(inp, b, th) : 0u;
            }
        } else {                          // fast path: read published chars
            s32[tid] = chars32[cbase + tid];
            if (tid < 2) {
                unsigned v = 0u;
                int gt = t0 + 1024 + tid * 4;
                if (gt < T_) v = chars32[cbase + 256 + tid];
                s32[256 + tid] = v;
            }
        }
        __syncthreads();
    }

    // ---------------- match (verbatim r5/r13) ----------------
    unsigned w0 = s32[tid], w1 = s32[tid + 1], w2 = s32[tid + 2];
    unsigned cw0 = w0;
    unsigned cw1 = __builtin_amdgcn_alignbyte(w1, w0, 1);
    unsigned cw2 = __builtin_amdgcn_alignbyte(w1, w0, 2);
    unsigned cw3 = __builtin_amdgcn_alignbyte(w1, w0, 3);
    unsigned cw4 = w1;
    unsigned cw5 = __builtin_amdgcn_alignbyte(w2, w1, 1);

    const uint4* tp = (const uint4*)s_tabs;
    float* obase = out + ((size_t)(b * N_ + n0)) * T_ + tb;
    bool tail = (tc == 7) && (tb + 3 >= TV_);

    #pragma unroll 4
    for (int g = 0; g < 32; ++g) {
        uint4 A  = tp[g * 3 + 0];         // xs0..xs3  (uniform -> broadcast)
        uint4 Bv = tp[g * 3 + 1];         // xs4, xs5, om0, om1
        uint4 Cv = tp[g * 3 + 2];         // om2..om5

        unsigned orv;
        orv  = ((cw0 ^ A.x)  + 0x7F7F7F7FU) & Bv.z;
        orv |= ((cw1 ^ A.y)  + 0x7F7F7F7FU) & Bv.w;   // v_and_or_b32
        orv |= ((cw2 ^ A.z)  + 0x7F7F7F7FU) & Cv.x;
        orv |= ((cw3 ^ A.w)  + 0x7F7F7F7FU) & Cv.y;
        orv |= ((cw4 ^ Bv.x) + 0x7F7F7F7FU) & Cv.z;
        orv |= ((cw5 ^ Bv.y) + 0x7F7F7F7FU) & Cv.w;

        float res[4];
        #pragma unroll
        for (int j = 0; j < 4; ++j)
            res[j] = (orv & (0x80u << (8 * j))) ? 0.0f : 1.0f;

        if (tail) {                       // only last chunk's tail lanes
            unsigned act = Bv.z | Bv.w | Cv.x | Cv.y | Cv.z | Cv.w;
            float padf = (act == 0u) ? 1.0f : 0.0f;  // psum==0: pad matches
            #pragma unroll
            for (int j = 0; j < 4; ++j)
                if (tb + j >= TV_) res[j] = padf;
        }

        float4 r; r.x = res[0]; r.y = res[1]; r.z = res[2]; r.w = res[3];
        *(float4*)(obase + (size_t)g * T_) = r;
    }
}

// ---------------------------------------------------------------------------
extern "C" void kernel_launch(void* const* d_in, const int* in_sizes, int n_in,
                              void* d_out, int out_size, void* d_ws, size_t ws_size,
                              hipStream_t stream) {
    const float* input_   = (const float*)d_in[0];   // (B,C,T,1) one-hot fp32
    const float* patterns = (const float*)d_in[1];   // (C,P,1,N) fp32
    float* out = (float*)d_out;                      // (B,N,T,1) fp32

    // ws layout: [8192, 9216) done flags (256 u32); [16384, +256K) chars
    unsigned* done    = (unsigned*)((char*)d_ws + 8192);
    unsigned* chars32 = (unsigned*)((char*)d_ws + 16384);

    hipLaunchKernelGGL(k_all, dim3(8, 8, B_), dim3(256), 0, stream,
                       input_, patterns, chars32, done, out);
}

// Round 19
// 112.785 us; speedup vs baseline: 1.6853x; 1.6853x over previous
//
#include <hip/hip_runtime.h>

// Problem constants (from reference)
#define B_ 32
#define C_ 32
#define T_ 8192
#define N_ 256
#define P_ 6
#define TV_ (T_ - P_ + 1)   // valid conv length = 8187
#define MAGIC 0x1B171D05u   // done-word sentinel (poison 0xAA.. != MAGIC)

// ---------------------------------------------------------------------------
// decode4: chars word covering t..t+3 of row b (sum_c c * onehot).
// ---------------------------------------------------------------------------
__device__ __forceinline__ unsigned decode4(const float* __restrict__ inp,
                                            int b, int t) {
    const float* base = inp + (size_t)b * C_ * T_ + t;
    float ax = 0.f, ay = 0.f, az = 0.f, aw = 0.f;
    #pragma unroll
    for (int c = 0; c < C_; ++c) {
        float4 v = *(const float4*)(base + (size_t)c * T_);
        float fc = (float)c;
        ax += fc * v.x; ay += fc * v.y; az += fc * v.z; aw += fc * v.w;
    }
    return ((unsigned)(ax + 0.5f))
         | ((unsigned)(ay + 0.5f) << 8)
         | ((unsigned)(az + 0.5f) << 16)
         | ((unsigned)(aw + 0.5f) << 24);
}

// ---------------------------------------------------------------------------
// k_all v2: r18 with the two mechanism fixes.
// Grid (tc=8, ng=8, b=32): linear id = tc + 8*(ng + 8*b). Producers (ng==0)
// have id = tc + 64*b -> id%8 = tc -> spread over ALL 8 XCDs (r18 bug: all
// producers on XCD0). Consumers spin with RELAXED agent loads (L3 read, no
// cache invalidate; r18 bug: acquire-per-iteration = buffer_inv storm), then
// ONE acquire load before consuming chars (covers first-replay poison-in-L2).
// Producer: decode chunk -> plain stores; __syncthreads drains vmcnt; tid0
// RELEASE-stores done[chunk] (agent release = L2 writeback, chars reach L3).
// Bounded spin -> idempotent self-decode fallback: correct under any
// scheduling (G16).
// ---------------------------------------------------------------------------
__global__ void k_all(const float* __restrict__ inp,
                      const float* __restrict__ pat,
                      unsigned* __restrict__ chars32,
                      unsigned* __restrict__ done,
                      float* __restrict__ out) {
    __shared__ unsigned s32[258];         // chars chunk + 2 halo words
    __shared__ unsigned s_tabs[32 * 12];  // this block's 32-n tab slice
    __shared__ int s_fb;                  // fallback flag

    int tc  = blockIdx.x;                 // 0..7 (t-chunk)  [swapped: XCD spread]
    int ng  = blockIdx.y;                 // 0..7 (n-group; ng==0 = producer)
    int b   = blockIdx.z;                 // 0..31
    int tid = threadIdx.x;
    int t0  = tc << 10;
    int tb  = t0 + (tid << 2);
    int n0  = ng << 5;
    int chunk = (b << 3) | tc;
    size_t cbase = ((size_t)b * T_ + t0) >> 2;

    if (ng == 0) {
        // ---------------- producer ----------------
        unsigned w = decode4(inp, b, tb);
        s32[tid] = w;
        chars32[cbase + tid] = w;
        if (tid < 2) {                    // own halo (local only)
            int th = t0 + 1024 + (tid << 2);
            s32[256 + tid] = (th < T_) ? decode4(inp, b, th) : 0u;
        }
        __syncthreads();                  // drains vmcnt: chars stores complete
        if (tid == 0)
            __hip_atomic_store(&done[chunk], MAGIC, __ATOMIC_RELEASE,
                               __HIP_MEMORY_SCOPE_AGENT);   // wb L2 -> L3
        // tabs for own (ng=0) slice, after publish
        if (tid < 192) {
            int nl = tid & 31, p = tid >> 5, n = n0 + nl;
            float maxv = -3.402823466e+38f, sum = 0.0f;
            unsigned mask = 0u;
            #pragma unroll
            for (int c = 0; c < C_; ++c) {
                float v = pat[((size_t)c * P_ + p) * N_ + n];
                sum += v;
                if (v > maxv) { maxv = v; mask = (1u << c); }
                else if (v == maxv) { mask |= (1u << c); }
            }
            if (!(sum > 0.0f)) mask = 0u;
            int pc = __popc(mask);
            unsigned req = (unsigned)(__ffs((int)mask) - 1);
            s_tabs[nl * 12 + p]     = (pc == 1) ? req * 0x01010101u : 0x7F7F7F7Fu;
            s_tabs[nl * 12 + 6 + p] = (pc == 0) ? 0u : 0x80808080u;
        }
        __syncthreads();
    } else {
        // ---------------- consumer ----------------
        if (tid == 0) s_fb = 0;
        if (tid < 192) {                  // tabs first: overlaps producer work
            int nl = tid & 31, p = tid >> 5, n = n0 + nl;
            float maxv = -3.402823466e+38f, sum = 0.0f;
            unsigned mask = 0u;
            #pragma unroll
            for (int c = 0; c < C_; ++c) {
                float v = pat[((size_t)c * P_ + p) * N_ + n];
                sum += v;
                if (v > maxv) { maxv = v; mask = (1u << c); }
                else if (v == maxv) { mask |= (1u << c); }
            }
            if (!(sum > 0.0f)) mask = 0u;
            int pc = __popc(mask);
            unsigned req = (unsigned)(__ffs((int)mask) - 1);
            s_tabs[nl * 12 + p]     = (pc == 1) ? req * 0x01010101u : 0x7F7F7F7Fu;
            s_tabs[nl * 12 + 6 + p] = (pc == 0) ? 0u : 0x80808080u;
        }
        __syncthreads();
        if (tid == 0) {                   // RELAXED spin: L3 read, no invalidate
            int it = 0;
            while (__hip_atomic_load(&done[chunk], __ATOMIC_RELAXED,
                                     __HIP_MEMORY_SCOPE_AGENT) != MAGIC) {
                __builtin_amdgcn_s_sleep(2);
                if (++it > (1 << 16)) { s_fb = 1; break; }
            }
            if (!s_fb)                    // ONE acquire: invalidate L1/L2
                (void)__hip_atomic_load(&done[chunk], __ATOMIC_ACQUIRE,
                                        __HIP_MEMORY_SCOPE_AGENT);
        }
        if (tid == 1 && tc < 7) {         // halo chunk
            int it = 0;
            int fb = 0;
            while (__hip_atomic_load(&done[chunk + 1], __ATOMIC_RELAXED,
                                     __HIP_MEMORY_SCOPE_AGENT) != MAGIC) {
                __builtin_amdgcn_s_sleep(2);
                if (++it > (1 << 16)) { fb = 1; s_fb = 1; break; }
            }
            if (!fb)
                (void)__hip_atomic_load(&done[chunk + 1], __ATOMIC_ACQUIRE,
                                        __HIP_MEMORY_SCOPE_AGENT);
        }
        __syncthreads();
        if (s_fb) {                       // deadlock-proof fallback: self-decode
            s32[tid] = decode4(inp, b, tb);
            if (tid < 2) {
                int th = t0 + 1024 + (tid << 2);
                s32[256 + tid] = (th < T_) ? decode4(inp, b, th) : 0u;
            }
        } else {                          // fast path: read published chars
            s32[tid] = chars32[cbase + tid];
            if (tid < 2) {
                unsigned v = 0u;
                int gt = t0 + 1024 + tid * 4;
                if (gt < T_) v = chars32[cbase + 256 + tid];
                s32[256 + tid] = v;
            }
        }
        __syncthreads();
    }

    // ---------------- match (verbatim r5/r13) ----------------
    unsigned w0 = s32[tid], w1 = s32[tid + 1], w2 = s32[tid + 2];
    unsigned cw0 = w0;
    unsigned cw1 = __builtin_amdgcn_alignbyte(w1, w0, 1);
    unsigned cw2 = __builtin_amdgcn_alignbyte(w1, w0, 2);
    unsigned cw3 = __builtin_amdgcn_alignbyte(w1, w0, 3);
    unsigned cw4 = w1;
    unsigned cw5 = __builtin_amdgcn_alignbyte(w2, w1, 1);

    const uint4* tp = (const uint4*)s_tabs;
    float* obase = out + ((size_t)(b * N_ + n0)) * T_ + tb;
    bool tail = (tc == 7) && (tb + 3 >= TV_);

    #pragma unroll 4
    for (int g = 0; g < 32; ++g) {
        uint4 A  = tp[g * 3 + 0];         // xs0..xs3  (uniform -> broadcast)
        uint4 Bv = tp[g * 3 + 1];         // xs4, xs5, om0, om1
        uint4 Cv = tp[g * 3 + 2];         // om2..om5

        unsigned orv;
        orv  = ((cw0 ^ A.x)  + 0x7F7F7F7FU) & Bv.z;
        orv |= ((cw1 ^ A.y)  + 0x7F7F7F7FU) & Bv.w;   // v_and_or_b32
        orv |= ((cw2 ^ A.z)  + 0x7F7F7F7FU) & Cv.x;
        orv |= ((cw3 ^ A.w)  + 0x7F7F7F7FU) & Cv.y;
        orv |= ((cw4 ^ Bv.x) + 0x7F7F7F7FU) & Cv.z;
        orv |= ((cw5 ^ Bv.y) + 0x7F7F7F7FU) & Cv.w;

        float res[4];
        #pragma unroll
        for (int j = 0; j < 4; ++j)
            res[j] = (orv & (0x80u << (8 * j))) ? 0.0f : 1.0f;

        if (tail) {                       // only last chunk's tail lanes
            unsigned act = Bv.z | Bv.w | Cv.x | Cv.y | Cv.z | Cv.w;
            float padf = (act == 0u) ? 1.0f : 0.0f;  // psum==0: pad matches
            #pragma unroll
            for (int j = 0; j < 4; ++j)
                if (tb + j >= TV_) res[j] = padf;
        }

        float4 r; r.x = res[0]; r.y = res[1]; r.z = res[2]; r.w = res[3];
        *(float4*)(obase + (size_t)g * T_) = r;
    }
}

// ---------------------------------------------------------------------------
extern "C" void kernel_launch(void* const* d_in, const int* in_sizes, int n_in,
                              void* d_out, int out_size, void* d_ws, size_t ws_size,
                              hipStream_t stream) {
    const float* input_   = (const float*)d_in[0];   // (B,C,T,1) one-hot fp32
    const float* patterns = (const float*)d_in[1];   // (C,P,1,N) fp32
    float* out = (float*)d_out;                      // (B,N,T,1) fp32

    // ws layout: [8192, 9216) done flags (256 u32); [16384, +256K) chars
    unsigned* done    = (unsigned*)((char*)d_ws + 8192);
    unsigned* chars32 = (unsigned*)((char*)d_ws + 16384);

    hipLaunchKernelGGL(k_all, dim3(8, 8, B_), dim3(256), 0, stream,
                       input_, patterns, chars32, done, out);
}

// Round 20
// 61.572 us; speedup vs baseline: 3.0870x; 1.8318x over previous
//
#include <hip/hip_runtime.h>

// Problem constants (from reference)
#define B_ 32
#define C_ 32
#define T_ 8192
#define N_ 256
#define P_ 6
#define TV_ (T_ - P_ + 1)   // valid conv length = 8187

// =============================================================================
// FINAL (r13 verbatim, 61.57us measured): 2-node pipeline.
//   k_chars: one-hot -> chars[B][T] (u8 packed u32), 256 blocks.
//   k_final: per-block in-LDS tab derivation from patterns + byte-SIMD match,
//            grid (8,8,32) = 2048 blocks, one float4 store/thread/n.
// k_final's store stream = 33.2us = write roofline (262MB @ 7.9TB/s, r6).
// The ~28us k_chars exposure is dispatch-structural: invariant to k_chars
// internals (r5 vs r9), 0.9us marginal steady-state (r15); all single-node
// alternatives (fused x5, coop, producer/consumer x2) measured worse
// (73-190us, rounds 7-19).
// =============================================================================

// ---------------------------------------------------------------------------
// Kernel 1: decode one-hot (B,C,T,1) -> chars[B][T] (u8 in u32).
// ---------------------------------------------------------------------------
__global__ void k_chars(const float* __restrict__ inp, unsigned* __restrict__ chars32) {
    int bx = blockIdx.x;                  // [0, B * T/1024)
    int b  = bx >> 3;                     // T/1024 = 8 chunks per batch
    int t  = ((bx & 7) << 10) + (threadIdx.x << 2);
    const float* base = inp + (size_t)b * C_ * T_ + t;
    float ax = 0.f, ay = 0.f, az = 0.f, aw = 0.f;
    #pragma unroll
    for (int c = 0; c < C_; ++c) {
        float4 v = *(const float4*)(base + (size_t)c * T_);
        float fc = (float)c;
        ax += fc * v.x; ay += fc * v.y; az += fc * v.z; aw += fc * v.w;
    }
    unsigned w = ((unsigned)(ax + 0.5f))
               | ((unsigned)(ay + 0.5f) << 8)
               | ((unsigned)(az + 0.5f) << 16)
               | ((unsigned)(aw + 0.5f) << 24);
    chars32[((size_t)b * T_ + t) >> 2] = w;
}

// ---------------------------------------------------------------------------
// Kernel 2: r5 k_final + in-block tab derivation (no k_disc node).
// Threads 0..191 derive one (p, n_local) table entry each from `pat`
// (pat = 192 KB -> L2-resident); single barrier covers chars staging + tabs.
// Match loop: byte-SIMD equality test, tabs broadcast from LDS.
// ---------------------------------------------------------------------------
__global__ void k_final(const unsigned char* __restrict__ chars,
                        const float* __restrict__ pat,
                        float* __restrict__ out) {
    __shared__ unsigned s32[258];         // 1024 chars + 8 halo bytes
    __shared__ unsigned s_tabs[32 * 12];  // this block's 32-n tab slice
    int tc  = blockIdx.x;                 // 0..7
    int ng  = blockIdx.y;                 // 0..7  (group of 32 n)
    int b   = blockIdx.z;                 // 0..31
    int tid = threadIdx.x;
    int t0  = tc << 10;
    int tb  = t0 + (tid << 2);
    int n0  = ng << 5;

    // ---- stage chars chunk ----
    const unsigned* csrc = (const unsigned*)(chars + (size_t)b * T_ + t0);
    s32[tid] = csrc[tid];
    if (tid < 2) {
        unsigned v = 0u;
        int gt = t0 + 1024 + tid * 4;     // byte index into chars[b][*]
        if (gt < T_) v = csrc[256 + tid];
        s32[256 + tid] = v;
    }

    // ---- derive this block's 32-n x 6-p tab slice ----
    if (tid < 192) {
        int nl = tid & 31;                // n_local
        int p  = tid >> 5;                // 0..5
        int n  = n0 + nl;
        float maxv = -3.402823466e+38f;
        float sum = 0.0f;
        unsigned mask = 0u;
        #pragma unroll
        for (int c = 0; c < C_; ++c) {
            float v = pat[((size_t)c * P_ + p) * N_ + n];
            sum += v;
            if (v > maxv) { maxv = v; mask = (1u << c); }
            else if (v == maxv) { mask |= (1u << c); }
        }
        if (!(sum > 0.0f)) mask = 0u;
        int pc = __popc(mask);
        unsigned req = (unsigned)(__ffs((int)mask) - 1);
        s_tabs[nl * 12 + p]     = (pc == 1) ? req * 0x01010101u : 0x7F7F7F7Fu;
        s_tabs[nl * 12 + 6 + p] = (pc == 0) ? 0u : 0x80808080u;
    }
    __syncthreads();

    // ---- match loop: byte-SIMD equality test ----
    unsigned w0 = s32[tid], w1 = s32[tid + 1], w2 = s32[tid + 2];
    unsigned cw0 = w0;
    unsigned cw1 = __builtin_amdgcn_alignbyte(w1, w0, 1);
    unsigned cw2 = __builtin_amdgcn_alignbyte(w1, w0, 2);
    unsigned cw3 = __builtin_amdgcn_alignbyte(w1, w0, 3);
    unsigned cw4 = w1;
    unsigned cw5 = __builtin_amdgcn_alignbyte(w2, w1, 1);

    const uint4* tp = (const uint4*)s_tabs;
    float* obase = out + ((size_t)(b * N_ + n0)) * T_ + tb;
    bool tail = (tc == 7) && (tb + 3 >= TV_);

    #pragma unroll 4
    for (int g = 0; g < 32; ++g) {
        uint4 A  = tp[g * 3 + 0];         // xs0..xs3  (uniform -> broadcast)
        uint4 Bv = tp[g * 3 + 1];         // xs4, xs5, om0, om1
        uint4 Cv = tp[g * 3 + 2];         // om2..om5

        unsigned orv;
        orv  = ((cw0 ^ A.x)  + 0x7F7F7F7FU) & Bv.z;
        orv |= ((cw1 ^ A.y)  + 0x7F7F7F7FU) & Bv.w;   // v_and_or_b32
        orv |= ((cw2 ^ A.z)  + 0x7F7F7F7FU) & Cv.x;
        orv |= ((cw3 ^ A.w)  + 0x7F7F7F7FU) & Cv.y;
        orv |= ((cw4 ^ Bv.x) + 0x7F7F7F7FU) & Cv.z;
        orv |= ((cw5 ^ Bv.y) + 0x7F7F7F7FU) & Cv.w;

        float res[4];
        #pragma unroll
        for (int j = 0; j < 4; ++j)
            res[j] = (orv & (0x80u << (8 * j))) ? 0.0f : 1.0f;

        if (tail) {                       // only last chunk's tail lanes
            unsigned act = Bv.z | Bv.w | Cv.x | Cv.y | Cv.z | Cv.w;
            float padf = (act == 0u) ? 1.0f : 0.0f;  // psum==0: pad matches
            #pragma unroll
            for (int j = 0; j < 4; ++j)
                if (tb + j >= TV_) res[j] = padf;
        }

        float4 r; r.x = res[0]; r.y = res[1]; r.z = res[2]; r.w = res[3];
        *(float4*)(obase + (size_t)g * T_) = r;
    }
}

// ---------------------------------------------------------------------------
extern "C" void kernel_launch(void* const* d_in, const int* in_sizes, int n_in,
                              void* d_out, int out_size, void* d_ws, size_t ws_size,
                              hipStream_t stream) {
    const float* input_   = (const float*)d_in[0];   // (B,C,T,1) one-hot fp32
    const float* patterns = (const float*)d_in[1];   // (C,P,1,N) fp32
    float* out = (float*)d_out;                      // (B,N,T,1) fp32

    // ws layout: [16384, 16384+256K) chars u8
    unsigned char* chars = (unsigned char*)d_ws + 16384;

    hipLaunchKernelGGL(k_chars, dim3(B_ * (T_ / 1024)), dim3(256), 0, stream,
                       input_, (unsigned*)chars);
    hipLaunchKernelGGL(k_final, dim3(T_ / 1024, N_ / 32, B_), dim3(256), 0, stream,
                       chars, patterns, out);
}